// Round 1
// baseline (953.739 us; speedup 1.0000x reference)
//
#include <hip/hip_runtime.h>
#include <math.h>

// ---------------------------------------------------------------------------
// texture_feature_extractor — MI355X HIP implementation
//
// Per-batch output layout (stride 791 floats):
//   [0..5]    pix: m, v, skew, kurt, min, max           (images, w240)
//   [6..21]   mean_mag:  ff*4 + o
//   [22..37]  mean_real: ff*4 + o
//   [38..47]  marg: i*2 + {skew, kurt}   (l0..l4)
//   [48]      hp_var
//   [49..448] mag_ac: ff*100 + o*25 + j  (zero-padded past n_uni)
//   [449..573] low_ac: i*25 + j
//   [574..598] hp_ac
//   [599..622] mag_within:  ff*6 + triu-pair
//   [623..646] real_within: ff*6 + triu-pair
//   [647..694] mag_across: (ff-1)*16 + o*4 + p
//   [695..790] ri_across: (ff-1)*32 + {rr:0,ri:16} + o*4 + p
//
// Key algebra: wcross(a,b,w) = sum(a*b*w) - sum(a*w)*sum(b*w)/sum(w); it is
// invariant to per-channel constant shifts, so magc/umagc mean-subtraction in
// the reference is skipped here. Same invariance holds for the autocorr crop
// (it re-subtracts the weighted crop mean internally).
//
// bbox geometry (verified vs Python round/ceil semantics, float-exact):
//   n=15  -> y0=5,  s=6      n=30  -> y0=9,  s=12
//   n=60  -> y0=18, s=24     n=120 -> y0=36, s=48     n=240 -> y0=72, s=96
// ---------------------------------------------------------------------------

#define PB 791  // per-batch output stride

__device__ __forceinline__ float wredsum(float v) {
#pragma unroll
  for (int off = 32; off > 0; off >>= 1) v += __shfl_down(v, off, 64);
  return v;
}
__device__ __forceinline__ float wredmin(float v) {
#pragma unroll
  for (int off = 32; off > 0; off >>= 1) v = fminf(v, __shfl_down(v, off, 64));
  return v;
}
__device__ __forceinline__ float wredmax(float v) {
#pragma unroll
  for (int off = 32; off > 0; off >>= 1) v = fmaxf(v, __shfl_down(v, off, 64));
  return v;
}

// gaussian line weight: exp(-c^2 / (2*sigma^2)), sigma=0.1 -> *50
__device__ __forceinline__ float gw(int i, float inv_n) {
  float c = ((float)i + 0.5f) * inv_n - 0.5f;
  return __expf(-c * c * 50.0f);
}

// ------------------------- weighted moments (stage 1) ----------------------
// grid = B*8, 256 threads. part: 8 floats per block: S1,S2,S3,S4,min,max
template <int N>
__global__ __launch_bounds__(256) void moments_partial(
    const float* __restrict__ in, float* __restrict__ part) {
  const int SPLIT = 8;
  int b = blockIdx.x / SPLIT, sp = blockIdx.x - b * SPLIT;
  const float* img = in + (size_t)b * (N * N);
  const float inv_n = 1.0f / N;
  float s1 = 0, s2 = 0, s3 = 0, s4 = 0, mn = INFINITY, mx = -INFINITY;
  for (int idx = sp * 256 + threadIdx.x; idx < N * N; idx += SPLIT * 256) {
    int i = idx / N, j = idx - i * N;
    float w = gw(i, inv_n) * gw(j, inv_n);
    float x = img[idx], x2 = x * x;
    s1 = fmaf(w, x, s1);
    s2 = fmaf(w, x2, s2);
    s3 = fmaf(w * x2, x, s3);
    s4 = fmaf(w * x2, x2, s4);
    mn = fminf(mn, x);
    mx = fmaxf(mx, x);
  }
  __shared__ float red[4][6];
  s1 = wredsum(s1); s2 = wredsum(s2); s3 = wredsum(s3); s4 = wredsum(s4);
  mn = wredmin(mn); mx = wredmax(mx);
  int lane = threadIdx.x & 63, wid = threadIdx.x >> 6;
  if (!lane) {
    red[wid][0] = s1; red[wid][1] = s2; red[wid][2] = s3;
    red[wid][3] = s4; red[wid][4] = mn; red[wid][5] = mx;
  }
  __syncthreads();
  if (threadIdx.x == 0) {
    float* dst = part + (size_t)blockIdx.x * 8;
    dst[0] = red[0][0] + red[1][0] + red[2][0] + red[3][0];
    dst[1] = red[0][1] + red[1][1] + red[2][1] + red[3][1];
    dst[2] = red[0][2] + red[1][2] + red[2][2] + red[3][2];
    dst[3] = red[0][3] + red[1][3] + red[2][3] + red[3][3];
    dst[4] = fminf(fminf(red[0][4], red[1][4]), fminf(red[2][4], red[3][4]));
    dst[5] = fmaxf(fmaxf(red[0][5], red[1][5]), fmaxf(red[2][5], red[3][5]));
  }
}

// grid = B, 64 threads; thread r handles region r:
// r=0 images->pix, r=1 hp->hp_var, r=2..6 lows->marg
__global__ void moments_final(const float* __restrict__ part,
                              float* __restrict__ out, int B) {
  int b = blockIdx.x;
  int r = threadIdx.x;
  if (r >= 7) return;
  const int ns[7] = {240, 240, 15, 30, 60, 120, 240};
  int n = ns[r];
  const float* p = part + ((size_t)r * B + b) * 64;  // 8 splits * 8 floats
  float s1 = 0, s2 = 0, s3 = 0, s4 = 0, mn = INFINITY, mx = -INFINITY;
  for (int sp = 0; sp < 8; ++sp) {
    s1 += p[sp * 8 + 0];
    s2 += p[sp * 8 + 1];
    s3 += p[sp * 8 + 2];
    s4 += p[sp * 8 + 3];
    mn = fminf(mn, p[sp * 8 + 4]);
    mx = fmaxf(mx, p[sp * 8 + 5]);
  }
  float sw = 0, inv_n = 1.0f / n;
  for (int i = 0; i < n; ++i) sw += gw(i, inv_n);
  float ws = sw * sw;
  float m = s1 / ws, E2 = s2 / ws, E3 = s3 / ws, E4 = s4 / ws;
  float v = E2 - m * m;
  float vs = fmaxf(v, 1e-12f);
  float mu3 = E3 - 3.0f * m * E2 + 2.0f * m * m * m;
  float mu4 = E4 - 4.0f * m * E3 + 6.0f * m * m * E2 - 3.0f * m * m * m * m;
  float sk = mu3 / (vs * sqrtf(vs));
  float ku = mu4 / (vs * vs);
  float* o = out + (size_t)b * PB;
  if (r == 0) {
    o[0] = m; o[1] = v; o[2] = sk; o[3] = ku; o[4] = mn; o[5] = mx;
  } else if (r == 1) {
    o[48] = v;
  } else {
    int i = r - 2;
    o[38 + i * 2] = sk;
    o[38 + i * 2 + 1] = ku;
  }
}

// --------------------- gram / cross-correlation (stage 1) ------------------
// acc layout: [0..3] sum w*mag_o   [4..7] sum w*re_o
//             [8..13] triu w*mag_o*mag_p   [14..19] triu w*re_o*re_p
// HASU adds:  [20..23] sum w*umag  [24..27] sum w*ur  [28..31] sum w*ui
//             [32..47] w*mag_o*umag_p  [48..63] w*re_o*ur_p  [64..79] w*re_o*ui_p
template <int N, bool HASU>
__global__ __launch_bounds__(256) void gram_partial(
    const float* __restrict__ cr, const float* __restrict__ ci,
    const float* __restrict__ ur, const float* __restrict__ ui,
    float* __restrict__ part) {
  const int SPLIT = 8;
  constexpr int NACC = HASU ? 80 : 20;
  int b = blockIdx.x / SPLIT, sp = blockIdx.x - b * SPLIT;
  const int npix = N * N;
  size_t base = (size_t)b * 4 * npix;
  const float inv_n = 1.0f / N;
  float acc[NACC];
#pragma unroll
  for (int a = 0; a < NACC; ++a) acc[a] = 0.f;
  for (int idx = sp * 256 + threadIdx.x; idx < npix; idx += SPLIT * 256) {
    int i = idx / N, j = idx - i * N;
    float w = gw(i, inv_n) * gw(j, inv_n);
    float mag[4], re[4], wmag[4], wre[4];
#pragma unroll
    for (int o = 0; o < 4; ++o) {
      float a_ = cr[base + (size_t)o * npix + idx];
      float b_ = ci[base + (size_t)o * npix + idx];
      re[o] = a_;
      mag[o] = sqrtf(a_ * a_ + b_ * b_);
      wmag[o] = w * mag[o];
      wre[o] = w * a_;
      acc[o] += wmag[o];
      acc[4 + o] += wre[o];
    }
    const int TI[6] = {0, 0, 0, 1, 1, 2};
    const int TJ[6] = {1, 2, 3, 2, 3, 3};
#pragma unroll
    for (int q = 0; q < 6; ++q) {
      acc[8 + q] = fmaf(wmag[TI[q]], mag[TJ[q]], acc[8 + q]);
      acc[14 + q] = fmaf(wre[TI[q]], re[TJ[q]], acc[14 + q]);
    }
    if (HASU) {
      float um[4], urv[4], uiv[4];
#pragma unroll
      for (int p_ = 0; p_ < 4; ++p_) {
        float a_ = ur[base + (size_t)p_ * npix + idx];
        float b_ = ui[base + (size_t)p_ * npix + idx];
        urv[p_] = a_;
        uiv[p_] = b_;
        um[p_] = sqrtf(a_ * a_ + b_ * b_);
        acc[20 + p_] = fmaf(w, um[p_], acc[20 + p_]);
        acc[24 + p_] = fmaf(w, a_, acc[24 + p_]);
        acc[28 + p_] = fmaf(w, b_, acc[28 + p_]);
      }
#pragma unroll
      for (int o = 0; o < 4; ++o) {
#pragma unroll
        for (int p_ = 0; p_ < 4; ++p_) {
          acc[32 + o * 4 + p_] = fmaf(wmag[o], um[p_], acc[32 + o * 4 + p_]);
          acc[48 + o * 4 + p_] = fmaf(wre[o], urv[p_], acc[48 + o * 4 + p_]);
          acc[64 + o * 4 + p_] = fmaf(wre[o], uiv[p_], acc[64 + o * 4 + p_]);
        }
      }
    }
  }
  __shared__ float red[4][NACC];
  int lane = threadIdx.x & 63, wid = threadIdx.x >> 6;
#pragma unroll
  for (int a = 0; a < NACC; ++a) {
    float v = wredsum(acc[a]);
    if (!lane) red[wid][a] = v;
  }
  __syncthreads();
  float* dst = part + (size_t)blockIdx.x * NACC;
  for (int a = threadIdx.x; a < NACC; a += 256)
    dst[a] = red[0][a] + red[1][a] + red[2][a] + red[3][a];
}

template <bool HASU>
__global__ void gram_final(const float* __restrict__ part,
                           float* __restrict__ out, int ff, int n) {
  constexpr int NACC = HASU ? 80 : 20;
  int b = blockIdx.x;
  __shared__ float tot[NACC];
  const float* p = part + (size_t)b * 8 * NACC;
  for (int a = threadIdx.x; a < NACC; a += blockDim.x) {
    float s = 0;
    for (int sp = 0; sp < 8; ++sp) s += p[sp * NACC + a];
    tot[a] = s;
  }
  __syncthreads();
  if (threadIdx.x == 0) {
    float sw = 0, inv_n = 1.0f / n;
    for (int i = 0; i < n; ++i) sw += gw(i, inv_n);
    float ws = sw * sw;
    float invws = 1.0f / ws;
    float scale = 1.0f / ((float)n * (float)n);
    float* o = out + (size_t)b * PB;
    for (int k = 0; k < 4; ++k) {
      o[6 + ff * 4 + k] = tot[k] * invws;
      o[22 + ff * 4 + k] = tot[4 + k] * invws;
    }
    const int TI[6] = {0, 0, 0, 1, 1, 2};
    const int TJ[6] = {1, 2, 3, 2, 3, 3};
    for (int q = 0; q < 6; ++q) {
      o[599 + ff * 6 + q] =
          (tot[8 + q] - tot[TI[q]] * tot[TJ[q]] * invws) * scale;
      o[623 + ff * 6 + q] =
          (tot[14 + q] - tot[4 + TI[q]] * tot[4 + TJ[q]] * invws) * scale;
    }
    if (HASU) {
      for (int oo = 0; oo < 4; ++oo) {
        for (int pp = 0; pp < 4; ++pp) {
          o[647 + (ff - 1) * 16 + oo * 4 + pp] =
              (tot[32 + oo * 4 + pp] - tot[oo] * tot[20 + pp] * invws) * scale;
          o[695 + (ff - 1) * 32 + oo * 4 + pp] =
              (tot[48 + oo * 4 + pp] - tot[4 + oo] * tot[24 + pp] * invws) *
              scale;
          o[695 + (ff - 1) * 32 + 16 + oo * 4 + pp] =
              (tot[64 + oo * 4 + pp] - tot[4 + oo] * tot[28 + pp] * invws) *
              scale;
        }
      }
    }
  }
}

// --------------------------- autocorrelation -------------------------------
// One block per (b, ch). Crop S x S staged in LDS, weighted+centered, then
// NUNI circular-lag dot products with static unrolled lags.
template <int OUTPIX, int S>
__global__ __launch_bounds__(256) void autocorr_k(
    const float* __restrict__ srcA, const float* __restrict__ srcB, int n,
    int C, int y0, float* __restrict__ out, int outBase) {
  constexpr int NUNI = (OUTPIX * OUTPIX + 1) / 2;
  constexpr int H = OUTPIX / 2;
  __shared__ float p[S * S];
  __shared__ float wv[S];
  __shared__ float red[4 * NUNI];  // NUNI>=5 so >=20 slots; phase1 uses [0..7]
  int b = blockIdx.x / C, ch = blockIdx.x - b * C;
  size_t off = ((size_t)b * C + ch) * ((size_t)n * n);
  int tid = threadIdx.x, lane = tid & 63, wid = tid >> 6;
  float inv_n = 1.0f / n;
  if (tid < S) wv[tid] = gw(y0 + tid, inv_n);
  __syncthreads();
  // phase 1: load crop, accumulate weighted sum + weight sum
  float spw = 0, sw = 0;
  for (int idx = tid; idx < S * S; idx += 256) {
    int i = idx / S, j = idx - i * S;
    size_t g = off + (size_t)(y0 + i) * n + (y0 + j);
    float v = srcA[g];
    if (srcB) {
      float y = srcB[g];
      v = sqrtf(v * v + y * y);
    }
    p[idx] = v;
    float w = wv[i] * wv[j];
    spw = fmaf(v, w, spw);
    sw += w;
  }
  spw = wredsum(spw);
  sw = wredsum(sw);
  if (!lane) {
    red[wid] = spw;
    red[4 + wid] = sw;
  }
  __syncthreads();
  float pm = (red[0] + red[1] + red[2] + red[3]) /
             (red[4] + red[5] + red[6] + red[7]);
  // phase 2: center + weight (each thread touches only its own elements)
  for (int idx = tid; idx < S * S; idx += 256) {
    int i = idx / S, j = idx - i * S;
    p[idx] = (p[idx] - pm) * wv[i] * wv[j];
  }
  __syncthreads();
  // phase 3: circular-lag dot products
  float acc[NUNI];
#pragma unroll
  for (int q = 0; q < NUNI; ++q) acc[q] = 0.f;
  for (int idx = tid; idx < S * S; idx += 256) {
    int i = idx / S, j = idx - i * S;
    float pv = p[idx];
#pragma unroll
    for (int q = 0; q < NUNI; ++q) {
      int dy = q / OUTPIX - H, dx = q % OUTPIX - H;
      int ii = i + dy;
      if (ii < 0) ii += S;
      if (ii >= S) ii -= S;
      int jj = j + dx;
      if (jj < 0) jj += S;
      if (jj >= S) jj -= S;
      acc[q] = fmaf(pv, p[ii * S + jj], acc[q]);
    }
  }
#pragma unroll
  for (int q = 0; q < NUNI; ++q) {
    float v = wredsum(acc[q]);
    if (!lane) red[q * 4 + wid] = v;
  }
  __syncthreads();
  float* o = out + (size_t)b * PB + outBase + ch * 25;
  if (tid < 25) {
    float v = 0.f;
    if (tid < NUNI)
      v = red[tid * 4] + red[tid * 4 + 1] + red[tid * 4 + 2] + red[tid * 4 + 3];
    o[tid] = v;  // zero-pad past NUNI (d_out is poisoned each call)
  }
}

// ---------------------------------------------------------------------------
extern "C" void kernel_launch(void* const* d_in, const int* in_sizes, int n_in,
                              void* d_out, int out_size, void* d_ws,
                              size_t ws_size, hipStream_t stream) {
  const float* images = (const float*)d_in[0];
  const float* hp = (const float*)d_in[1];
  const float* l0 = (const float*)d_in[2];
  const float* l1 = (const float*)d_in[3];
  const float* l2 = (const float*)d_in[4];
  const float* l3 = (const float*)d_in[5];
  const float* l4 = (const float*)d_in[6];
  const float* cr0 = (const float*)d_in[7];
  const float* cr1 = (const float*)d_in[8];
  const float* cr2 = (const float*)d_in[9];
  const float* cr3 = (const float*)d_in[10];
  const float* ci0 = (const float*)d_in[11];
  const float* ci1 = (const float*)d_in[12];
  const float* ci2 = (const float*)d_in[13];
  const float* ci3 = (const float*)d_in[14];
  const float* ur1 = (const float*)d_in[15];
  const float* ur2 = (const float*)d_in[16];
  const float* ur3 = (const float*)d_in[17];
  const float* ui1 = (const float*)d_in[18];
  const float* ui2 = (const float*)d_in[19];
  const float* ui3 = (const float*)d_in[20];
  float* out = (float*)d_out;
  int B = in_sizes[0] / (240 * 240);

  float* wsf = (float*)d_ws;
  float* momPart = wsf;                          // 7 regions * B*8*8
  float* g0 = momPart + (size_t)7 * B * 64;      // B*8*20
  float* g1 = g0 + (size_t)B * 8 * 20;           // B*8*80
  float* g2 = g1 + (size_t)B * 8 * 80;
  float* g3 = g2 + (size_t)B * 8 * 80;

  // weighted moments (pix / hp_var / marg)
  moments_partial<240><<<B * 8, 256, 0, stream>>>(images, momPart + (size_t)0 * B * 64);
  moments_partial<240><<<B * 8, 256, 0, stream>>>(hp, momPart + (size_t)1 * B * 64);
  moments_partial<15><<<B * 8, 256, 0, stream>>>(l0, momPart + (size_t)2 * B * 64);
  moments_partial<30><<<B * 8, 256, 0, stream>>>(l1, momPart + (size_t)3 * B * 64);
  moments_partial<60><<<B * 8, 256, 0, stream>>>(l2, momPart + (size_t)4 * B * 64);
  moments_partial<120><<<B * 8, 256, 0, stream>>>(l3, momPart + (size_t)5 * B * 64);
  moments_partial<240><<<B * 8, 256, 0, stream>>>(l4, momPart + (size_t)6 * B * 64);
  moments_final<<<B, 64, 0, stream>>>(momPart, out, B);

  // gram / cross terms (mean_mag, mean_real, within, across)
  gram_partial<30, false><<<B * 8, 256, 0, stream>>>(cr0, ci0, nullptr, nullptr, g0);
  gram_partial<60, true><<<B * 8, 256, 0, stream>>>(cr1, ci1, ur1, ui1, g1);
  gram_partial<120, true><<<B * 8, 256, 0, stream>>>(cr2, ci2, ur2, ui2, g2);
  gram_partial<240, true><<<B * 8, 256, 0, stream>>>(cr3, ci3, ur3, ui3, g3);
  gram_final<false><<<B, 128, 0, stream>>>(g0, out, 0, 30);
  gram_final<true><<<B, 128, 0, stream>>>(g1, out, 1, 60);
  gram_final<true><<<B, 128, 0, stream>>>(g2, out, 2, 120);
  gram_final<true><<<B, 128, 0, stream>>>(g3, out, 3, 240);

  // autocorrelations (direct circular lags, crop in LDS)
  autocorr_k<7, 96><<<B, 256, 0, stream>>>(hp, nullptr, 240, 1, 72, out, 574);
  autocorr_k<3, 6><<<B, 256, 0, stream>>>(l0, nullptr, 15, 1, 5, out, 449);
  autocorr_k<3, 12><<<B, 256, 0, stream>>>(l1, nullptr, 30, 1, 9, out, 474);
  autocorr_k<5, 24><<<B, 256, 0, stream>>>(l2, nullptr, 60, 1, 18, out, 499);
  autocorr_k<7, 48><<<B, 256, 0, stream>>>(l3, nullptr, 120, 1, 36, out, 524);
  autocorr_k<7, 96><<<B, 256, 0, stream>>>(l4, nullptr, 240, 1, 72, out, 549);
  autocorr_k<3, 12><<<B * 4, 256, 0, stream>>>(cr0, ci0, 30, 4, 9, out, 49);
  autocorr_k<5, 24><<<B * 4, 256, 0, stream>>>(cr1, ci1, 60, 4, 18, out, 149);
  autocorr_k<7, 48><<<B * 4, 256, 0, stream>>>(cr2, ci2, 120, 4, 36, out, 249);
  autocorr_k<7, 96><<<B * 4, 256, 0, stream>>>(cr3, ci3, 240, 4, 72, out, 349);
}